// Round 4
// baseline (179.379 us; speedup 1.0000x reference)
//
#include <hip/hip_runtime.h>

#define N_NODES 100000
#define N_EDGES 1600000
#define IN_H 18
#define OUT_H 11
#define NCLASS 40
#define NHID 256
#define PSTRIDE 16            // 11 features + dinv + pad -> 64B rows (one cache line)

// ---- bucket-sort geometry ----
#define BBITS 9
#define BINS 512
#define NB 196                              // ceil(100000/512)
#define NBLK 800
#define CHUNK 2000                          // NBLK*CHUNK == N_EDGES
#define SRC_MASK 0x1FFFF

// ---------------- K1a: per-block bucket histogram (LDS atomics only) ----------------
__global__ void k_hist(const int* __restrict__ dst, int* __restrict__ bh, int E) {
    __shared__ int h[NB];
    int t = threadIdx.x;
    if (t < NB) h[t] = 0;
    __syncthreads();
    int base = blockIdx.x * CHUNK;
    int end = base + CHUNK; if (end > E) end = E;
    for (int i = base + t; i < end; i += blockDim.x)
        atomicAdd(&h[dst[i] >> BBITS], 1);
    __syncthreads();
    if (t < NB) bh[t * NBLK + blockIdx.x] = h[t];   // [bin][blk]
}

// ---------------- S1: bucket totals ----------------
__global__ void k_btot(const int* __restrict__ bh, int* __restrict__ btot) {
    __shared__ int s[256];
    int b = blockIdx.x, t = threadIdx.x;
    int sum = 0;
    for (int k = t; k < NBLK; k += 256) sum += bh[b * NBLK + k];
    s[t] = sum;
    __syncthreads();
    for (int off = 128; off > 0; off >>= 1) {
        if (t < off) s[t] += s[t + off];
        __syncthreads();
    }
    if (t == 0) btot[b] = s[0];
}

// ---------------- S2: exclusive scan of bucket totals ----------------
__global__ void k_bstart(const int* __restrict__ btot, int* __restrict__ bstart) {
    if (threadIdx.x == 0 && blockIdx.x == 0) {
        int run = 0;
        for (int b = 0; b < NB; ++b) { bstart[b] = run; run += btot[b]; }
        bstart[NB] = run;
    }
}

// ---------------- S3: per-(bin,blk) absolute offsets, in place ----------------
__global__ __launch_bounds__(1024) void k_boff(int* __restrict__ bh,
                                               const int* __restrict__ bstart) {
    __shared__ int s0[1024], s1[1024];
    int b = blockIdx.x, t = threadIdx.x;
    int v = (t < NBLK) ? bh[b * NBLK + t] : 0;
    s0[t] = v;
    __syncthreads();
    int* c = s0; int* n = s1;
    for (int off = 1; off < 1024; off <<= 1) {
        n[t] = c[t] + ((t >= off) ? c[t - off] : 0);
        __syncthreads();
        int* tmp = c; c = n; n = tmp;
    }
    if (t < NBLK) bh[b * NBLK + t] = c[t] - v + bstart[b];
}

// ---------------- K1c: scatter edges into buckets (LDS cursors) ----------------
__global__ void k_bucket(const int* __restrict__ ei, const int* __restrict__ bh,
                         unsigned int* __restrict__ packed, int E) {
    __shared__ int cur[NB];
    int t = threadIdx.x;
    if (t < NB) cur[t] = bh[t * NBLK + blockIdx.x];
    __syncthreads();
    int base = blockIdx.x * CHUNK;
    int end = base + CHUNK; if (end > E) end = E;
    for (int i = base + t; i < end; i += blockDim.x) {
        int s = ei[i];
        int d = ei[E + i];
        int slot = atomicAdd(&cur[d >> BBITS], 1);
        packed[slot] = ((unsigned)(d & (BINS - 1)) << 17) | (unsigned)s;
    }
}

// ---------------- K2: per-bucket counting sort -> col, rowptr, dinv ----------------
__global__ __launch_bounds__(1024)
void k_sort(const unsigned int* __restrict__ packed, const int* __restrict__ bstart,
            int* __restrict__ col, int* __restrict__ rowptr, float* __restrict__ dinv) {
    __shared__ int hist[BINS];
    __shared__ int s0[BINS], s1[BINS];
    __shared__ int cur[BINS];
    int b = blockIdx.x, t = threadIdx.x;
    int beg = bstart[b], end = bstart[b + 1];
    if (t < BINS) hist[t] = 0;
    __syncthreads();
    for (int i = beg + t; i < end; i += blockDim.x)
        atomicAdd(&hist[packed[i] >> 17], 1);
    __syncthreads();
    if (t < BINS) s0[t] = hist[t];
    __syncthreads();
    int* c = s0; int* n = s1;
    for (int off = 1; off < BINS; off <<= 1) {
        if (t < BINS) n[t] = c[t] + ((t >= off) ? c[t - off] : 0);
        __syncthreads();
        int* tmp = c; c = n; n = tmp;
    }
    if (t < BINS) {
        int excl = c[t] - hist[t];
        int gbase = beg + excl;
        cur[t] = gbase;
        int node = (b << BBITS) + t;
        if (node <= N_NODES) rowptr[node] = gbase;
        if (node < N_NODES)  dinv[node] = rsqrtf((float)(hist[t] + 1));
    }
    __syncthreads();
    for (int i = beg + t; i < end; i += blockDim.x) {
        unsigned p = packed[i];
        int slot = atomicAdd(&cur[p >> 17], 1);
        col[slot] = (int)(p & SRC_MASK);
    }
}

// ---------------- W12 = W1 @ W2, bb = b1 @ W2 (one block) ----------------
__global__ void k_w12(const float* __restrict__ W1, const float* __restrict__ b1,
                      const float* __restrict__ W2,
                      float* __restrict__ W12, float* __restrict__ bb) {
    int t = threadIdx.x;
    if (t < IN_H * OUT_H) {
        int i = t / OUT_H, j = t % OUT_H;
        float s = 0.f;
        for (int k = 0; k < NHID; ++k) s += W1[i * NHID + k] * W2[k * OUT_H + j];
        W12[t] = s;
    } else if (t < IN_H * OUT_H + OUT_H) {
        int j = t - IN_H * OUT_H;
        float s = 0.f;
        for (int k = 0; k < NHID; ++k) s += b1[k] * W2[k * OUT_H + j];
        bb[j] = s;
    }
}

// ---------------- P' rows: [dinv*(X@W12) (11), dinv, 0,0,0,0] ----------------
__global__ void k_P(const float* __restrict__ X, const float* __restrict__ W12g,
                    const float* __restrict__ dinv, float* __restrict__ Pp, int n) {
    __shared__ float sW[IN_H * OUT_H];
    int t = threadIdx.x;
    if (t < IN_H * OUT_H) sW[t] = W12g[t];
    __syncthreads();
    int v = blockIdx.x * blockDim.x + t;
    if (v >= n) return;
    float x[IN_H];
    const float2* xr = (const float2*)(X + (size_t)v * IN_H);
    #pragma unroll
    for (int k = 0; k < IN_H / 2; ++k) {
        float2 c = xr[k];
        x[2 * k] = c.x; x[2 * k + 1] = c.y;
    }
    float dv = dinv[v];
    float* pr = Pp + (size_t)v * PSTRIDE;
    #pragma unroll
    for (int j = 0; j < OUT_H; ++j) {
        float s = 0.f;
        #pragma unroll
        for (int k = 0; k < IN_H; ++k) s += x[k] * sW[k * OUT_H + j];
        pr[j] = dv * s;
    }
    pr[11] = dv;            // fold dinv into the row (summed as "feature 11")
    pr[12] = 0.f; pr[13] = 0.f; pr[14] = 0.f; pr[15] = 0.f;
}

// ---------------- gather pass 1 (4 lanes/node): Z1' = dinv^2*(ÂP'), r ----------------
__global__ void k_gather1(const int* __restrict__ rowptr, const int* __restrict__ col,
                          const float* __restrict__ dinv, const float* __restrict__ Pp,
                          float* __restrict__ Z1p, float* __restrict__ r, int n) {
    int g = blockIdx.x * blockDim.x + threadIdx.x;
    int v = g >> 2;
    int lane = g & 3;
    if (v >= n) return;
    int beg = rowptr[v], end = rowptr[v + 1];
    float4 acc = make_float4(0.f, 0.f, 0.f, 0.f);
    const float4* P4 = (const float4*)Pp;
    int e = beg;
    for (; e + 1 < end; e += 2) {
        int s0 = col[e], s1 = col[e + 1];
        float4 a = P4[(size_t)s0 * 4 + lane];
        float4 b = P4[(size_t)s1 * 4 + lane];
        acc.x += a.x; acc.y += a.y; acc.z += a.z; acc.w += a.w;
        acc.x += b.x; acc.y += b.y; acc.z += b.z; acc.w += b.w;
    }
    if (e < end) {
        float4 a = P4[(size_t)col[e] * 4 + lane];
        acc.x += a.x; acc.y += a.y; acc.z += a.z; acc.w += a.w;
    }
    {   // self-loop
        float4 a = P4[(size_t)v * 4 + lane];
        acc.x += a.x; acc.y += a.y; acc.z += a.z; acc.w += a.w;
    }
    float dd = dinv[v];
    float s2 = dd * dd;
    float4 z = make_float4(s2 * acc.x, s2 * acc.y, s2 * acc.z, s2 * acc.w);
    ((float4*)Z1p)[(size_t)v * 4 + lane] = z;
    if (lane == 2) r[v] = dd * acc.w;   // acc.w = sum dinv[src] + dinv[v]
}

// ---------------- final (4 lanes/node): gather Z1', relu, fused matmul ----------------
__global__ void k_final(const int* __restrict__ rowptr, const int* __restrict__ col,
                        const float* __restrict__ dinv, const float* __restrict__ Z1p,
                        const float* __restrict__ r, const float* __restrict__ bbg,
                        const float* __restrict__ b2g, const float* __restrict__ emb_a,
                        const float* __restrict__ Wc, const float* __restrict__ bc,
                        float* __restrict__ out, int n) {
    __shared__ float sWc[(NCLASS + OUT_H) * NCLASS];   // 51*40 = 2040
    __shared__ float sbc[NCLASS];
    __shared__ float sb2[OUT_H];
    __shared__ float sbb[OUT_H];
    for (int t = threadIdx.x; t < (NCLASS + OUT_H) * NCLASS; t += blockDim.x) sWc[t] = Wc[t];
    if (threadIdx.x < NCLASS) sbc[threadIdx.x] = bc[threadIdx.x];
    if (threadIdx.x < OUT_H) { sb2[threadIdx.x] = b2g[threadIdx.x]; sbb[threadIdx.x] = bbg[threadIdx.x]; }
    __syncthreads();
    int g = blockIdx.x * blockDim.x + threadIdx.x;
    int v = g >> 2;
    int lane = g & 3;
    if (v >= n) return;
    int beg = rowptr[v], end = rowptr[v + 1];
    float4 acc = make_float4(0.f, 0.f, 0.f, 0.f);
    const float4* Z4 = (const float4*)Z1p;
    int e = beg;
    for (; e + 1 < end; e += 2) {
        int s0 = col[e], s1 = col[e + 1];
        float4 a = Z4[(size_t)s0 * 4 + lane];
        float4 b = Z4[(size_t)s1 * 4 + lane];
        acc.x += a.x; acc.y += a.y; acc.z += a.z; acc.w += a.w;
        acc.x += b.x; acc.y += b.y; acc.z += b.z; acc.w += b.w;
    }
    if (e < end) {
        float4 a = Z4[(size_t)col[e] * 4 + lane];
        acc.x += a.x; acc.y += a.y; acc.z += a.z; acc.w += a.w;
    }
    {
        float4 a = Z4[(size_t)v * 4 + lane];
        acc.x += a.x; acc.y += a.y; acc.z += a.z; acc.w += a.w;
    }
    float dd = dinv[v];
    float rv = r[v];
    // h features owned by this lane: f = 4*lane + c  (lane2: 3 valid, lane3: 0)
    float h[4];
    float af[4] = {acc.x, acc.y, acc.z, acc.w};
    int hn = (lane < 2) ? 4 : (lane == 2 ? 3 : 0);
    #pragma unroll
    for (int c = 0; c < 4; ++c) {
        int f = 4 * lane + c;
        if (c < hn) {
            float tv = dd * af[c] + rv * sbb[f] + sb2[f];
            h[c] = tv > 0.f ? tv : 0.f;
        } else h[c] = 0.f;
    }
    // k-split matmul: lane covers emb k = lane+4t (t=0..9) and its own h k's
    float o[NCLASS];
    #pragma unroll
    for (int j = 0; j < NCLASS; ++j) o[j] = 0.f;
    const float* ea = emb_a + (size_t)v * NCLASS;
    #pragma unroll
    for (int t10 = 0; t10 < 10; ++t10) {
        int k = lane + 4 * t10;
        float a = ea[k];                       // 16B coalesced per 4-lane group
        const float* wrow = &sWc[k * NCLASS];
        #pragma unroll
        for (int j = 0; j < NCLASS; ++j) o[j] += a * wrow[j];
    }
    #pragma unroll
    for (int c = 0; c < 4; ++c) {
        if (c < hn) {
            const float* wrow = &sWc[(NCLASS + 4 * lane + c) * NCLASS];
            float hv = h[c];
            #pragma unroll
            for (int j = 0; j < NCLASS; ++j) o[j] += hv * wrow[j];
        }
    }
    // butterfly reduce across the 4-lane group
    #pragma unroll
    for (int j = 0; j < NCLASS; ++j) {
        o[j] += __shfl_xor(o[j], 1);
        o[j] += __shfl_xor(o[j], 2);
    }
    // lane writes its 10-float slice (+bc), float2-aligned
    float* orow = out + (size_t)v * NCLASS + 10 * lane;
    #pragma unroll
    for (int j2 = 0; j2 < 5; ++j2) {
        int j = 10 * lane + 2 * j2;
        float2 w = make_float2(o[j] + sbc[j], o[j + 1] + sbc[j + 1]);
        *(float2*)(orow + 2 * j2) = w;
    }
}

extern "C" void kernel_launch(void* const* d_in, const int* in_sizes, int n_in,
                              void* d_out, int out_size, void* d_ws, size_t ws_size,
                              hipStream_t stream) {
    const float* X     = (const float*)d_in[0];
    const int*   ei    = (const int*)d_in[1];
    const float* emb_a = (const float*)d_in[2];
    const float* W1    = (const float*)d_in[3];
    const float* b1    = (const float*)d_in[4];
    const float* W2    = (const float*)d_in[5];
    const float* b2    = (const float*)d_in[6];
    const float* Wc    = (const float*)d_in[7];
    const float* bc    = (const float*)d_in[8];
    float* out = (float*)d_out;

    char* ws = (char*)d_ws;
    size_t off = 0;
    auto alloc = [&](size_t nbytes) {
        void* p = (void*)(ws + off);
        off += ((nbytes + 255) / 256) * 256;
        return p;
    };
    // bh dead after k_bucket -> rvec aliases it. packed dead after k_sort -> Pp aliases it.
    char* bh_base = (char*)alloc((size_t)NB * NBLK * sizeof(int));        // 627 KB
    int*   bh     = (int*)bh_base;
    float* rvec   = (float*)bh_base;
    int*   btot   = (int*)  alloc(NB * sizeof(int));
    int*   bstart = (int*)  alloc((NB + 1) * sizeof(int));
    char* pk_base = (char*)alloc((size_t)N_EDGES * sizeof(unsigned int)); // 6.4 MB
    unsigned int* packed = (unsigned int*)pk_base;
    float* Pp     = (float*)pk_base;                                      // 6.4 MB alias
    int*   col    = (int*)  alloc((size_t)N_EDGES * sizeof(int));
    int*   rowptr = (int*)  alloc((N_NODES + 1) * sizeof(int));
    float* dinv   = (float*)alloc(N_NODES * sizeof(float));
    float* W12    = (float*)alloc(IN_H * OUT_H * sizeof(float));
    float* bb     = (float*)alloc(OUT_H * sizeof(float));
    float* Z1p    = (float*)alloc((size_t)N_NODES * PSTRIDE * sizeof(float));

    const int B = 256;
    int gN  = (N_NODES + B - 1) / B;            // thread per node
    int gN4 = (N_NODES * 4 + B - 1) / B;        // 4 lanes per node

    k_hist   <<<NBLK, B, 0, stream>>>(ei + N_EDGES, bh, N_EDGES);
    k_btot   <<<NB, 256, 0, stream>>>(bh, btot);
    k_bstart <<<1, 64, 0, stream>>>(btot, bstart);
    k_boff   <<<NB, 1024, 0, stream>>>(bh, bstart);
    k_bucket <<<NBLK, B, 0, stream>>>(ei, bh, packed, N_EDGES);
    k_sort   <<<NB, 1024, 0, stream>>>(packed, bstart, col, rowptr, dinv);
    k_w12    <<<1, B, 0, stream>>>(W1, b1, W2, W12, bb);
    k_P      <<<gN, B, 0, stream>>>(X, W12, dinv, Pp, N_NODES);
    k_gather1<<<gN4, B, 0, stream>>>(rowptr, col, dinv, Pp, Z1p, rvec, N_NODES);
    k_final  <<<gN4, B, 0, stream>>>(rowptr, col, dinv, Z1p, rvec, bb, b2, emb_a,
                                     Wc, bc, out, N_NODES);
}

// Round 5
// 136.415 us; speedup vs baseline: 1.3149x; 1.3149x over previous
//
#include <hip/hip_runtime.h>

#define N_NODES 100000
#define N_EDGES 1600000
#define IN_H 18
#define OUT_H 11
#define NCLASS 40
#define NHID 256
#define PSTRIDE 16            // P'/Z1' rows: 11 feat + dinv + pad -> 64B (one line)
#define HSTRIDE 12            // H2' rows: 11 feat + pad -> 48B

// ---- bucket-sort geometry ----
#define BBITS 9
#define BINS 512
#define NB 196                              // ceil(100000/512)
#define NBLK 800
#define CHUNK 2000                          // NBLK*CHUNK == N_EDGES; 2000%4==0
#define SRC_MASK 0x1FFFF

// ---------------- K1a: per-block bucket histogram (LDS atomics only) ----------------
__global__ void k_hist(const int* __restrict__ dst, int* __restrict__ bh, int E) {
    __shared__ int h[NB];
    int t = threadIdx.x;
    if (t < NB) h[t] = 0;
    __syncthreads();
    const int4* d4 = (const int4*)(dst + blockIdx.x * CHUNK);   // 8000B offset, 16B aligned
    for (int i = t; i < CHUNK / 4; i += blockDim.x) {
        int4 w = d4[i];
        atomicAdd(&h[w.x >> BBITS], 1);
        atomicAdd(&h[w.y >> BBITS], 1);
        atomicAdd(&h[w.z >> BBITS], 1);
        atomicAdd(&h[w.w >> BBITS], 1);
    }
    __syncthreads();
    if (t < NB) bh[t * NBLK + blockIdx.x] = h[t];   // [bin][blk]
}

// ---------------- S1: bucket totals ----------------
__global__ void k_btot(const int* __restrict__ bh, int* __restrict__ btot) {
    __shared__ int s[256];
    int b = blockIdx.x, t = threadIdx.x;
    int sum = 0;
    for (int k = t; k < NBLK; k += 256) sum += bh[b * NBLK + k];
    s[t] = sum;
    __syncthreads();
    for (int off = 128; off > 0; off >>= 1) {
        if (t < off) s[t] += s[t + off];
        __syncthreads();
    }
    if (t == 0) btot[b] = s[0];
}

// ---------------- S2: exclusive scan of bucket totals ----------------
__global__ void k_bstart(const int* __restrict__ btot, int* __restrict__ bstart) {
    if (threadIdx.x == 0 && blockIdx.x == 0) {
        int run = 0;
        for (int b = 0; b < NB; ++b) { bstart[b] = run; run += btot[b]; }
        bstart[NB] = run;
    }
}

// ---------------- S3: per-(bin,blk) absolute offsets, in place ----------------
__global__ __launch_bounds__(1024) void k_boff(int* __restrict__ bh,
                                               const int* __restrict__ bstart) {
    __shared__ int s0[1024], s1[1024];
    int b = blockIdx.x, t = threadIdx.x;
    int v = (t < NBLK) ? bh[b * NBLK + t] : 0;
    s0[t] = v;
    __syncthreads();
    int* c = s0; int* n = s1;
    for (int off = 1; off < 1024; off <<= 1) {
        n[t] = c[t] + ((t >= off) ? c[t - off] : 0);
        __syncthreads();
        int* tmp = c; c = n; n = tmp;
    }
    if (t < NBLK) bh[b * NBLK + t] = c[t] - v + bstart[b];
}

// ---------------- K1c: scatter edges into buckets (LDS cursors) ----------------
__global__ void k_bucket(const int* __restrict__ ei, const int* __restrict__ bh,
                         unsigned int* __restrict__ packed, int E) {
    __shared__ int cur[NB];
    int t = threadIdx.x;
    if (t < NB) cur[t] = bh[t * NBLK + blockIdx.x];
    __syncthreads();
    int base = blockIdx.x * CHUNK;
    const int4* s4 = (const int4*)(ei + base);
    const int4* d4 = (const int4*)(ei + E + base);
    for (int i = t; i < CHUNK / 4; i += blockDim.x) {
        int4 s = s4[i];
        int4 d = d4[i];
        int sl;
        sl = atomicAdd(&cur[d.x >> BBITS], 1);
        packed[sl] = ((unsigned)(d.x & (BINS - 1)) << 17) | (unsigned)s.x;
        sl = atomicAdd(&cur[d.y >> BBITS], 1);
        packed[sl] = ((unsigned)(d.y & (BINS - 1)) << 17) | (unsigned)s.y;
        sl = atomicAdd(&cur[d.z >> BBITS], 1);
        packed[sl] = ((unsigned)(d.z & (BINS - 1)) << 17) | (unsigned)s.z;
        sl = atomicAdd(&cur[d.w >> BBITS], 1);
        packed[sl] = ((unsigned)(d.w & (BINS - 1)) << 17) | (unsigned)s.w;
    }
}

// ---------------- K2: per-bucket counting sort -> col, rowptr, dinv ----------------
__global__ __launch_bounds__(1024)
void k_sort(const unsigned int* __restrict__ packed, const int* __restrict__ bstart,
            int* __restrict__ col, int* __restrict__ rowptr, float* __restrict__ dinv) {
    __shared__ int hist[BINS];
    __shared__ int s0[BINS], s1[BINS];
    __shared__ int cur[BINS];
    int b = blockIdx.x, t = threadIdx.x;
    int beg = bstart[b], end = bstart[b + 1];
    if (t < BINS) hist[t] = 0;
    __syncthreads();
    for (int i = beg + t; i < end; i += blockDim.x)
        atomicAdd(&hist[packed[i] >> 17], 1);
    __syncthreads();
    if (t < BINS) s0[t] = hist[t];
    __syncthreads();
    int* c = s0; int* n = s1;
    for (int off = 1; off < BINS; off <<= 1) {
        if (t < BINS) n[t] = c[t] + ((t >= off) ? c[t - off] : 0);
        __syncthreads();
        int* tmp = c; c = n; n = tmp;
    }
    if (t < BINS) {
        int excl = c[t] - hist[t];
        int gbase = beg + excl;
        cur[t] = gbase;
        int node = (b << BBITS) + t;
        if (node <= N_NODES) rowptr[node] = gbase;
        if (node < N_NODES)  dinv[node] = rsqrtf((float)(hist[t] + 1));
    }
    __syncthreads();
    for (int i = beg + t; i < end; i += blockDim.x) {
        unsigned p = packed[i];
        int slot = atomicAdd(&cur[p >> 17], 1);
        col[slot] = (int)(p & SRC_MASK);
    }
}

// ---------------- W12 = W1 @ W2, bb = b1 @ W2 (one block) ----------------
__global__ void k_w12(const float* __restrict__ W1, const float* __restrict__ b1,
                      const float* __restrict__ W2,
                      float* __restrict__ W12, float* __restrict__ bb) {
    int t = threadIdx.x;
    if (t < IN_H * OUT_H) {
        int i = t / OUT_H, j = t % OUT_H;
        float s = 0.f;
        for (int k = 0; k < NHID; ++k) s += W1[i * NHID + k] * W2[k * OUT_H + j];
        W12[t] = s;
    } else if (t < IN_H * OUT_H + OUT_H) {
        int j = t - IN_H * OUT_H;
        float s = 0.f;
        for (int k = 0; k < NHID; ++k) s += b1[k] * W2[k * OUT_H + j];
        bb[j] = s;
    }
}

// ---------------- P' rows: [dinv*(X@W12) (11), dinv, 0,0,0,0] ----------------
__global__ void k_P(const float* __restrict__ X, const float* __restrict__ W12g,
                    const float* __restrict__ dinv, float* __restrict__ Pp, int n) {
    __shared__ float sW[IN_H * OUT_H];
    int t = threadIdx.x;
    if (t < IN_H * OUT_H) sW[t] = W12g[t];
    __syncthreads();
    int v = blockIdx.x * blockDim.x + t;
    if (v >= n) return;
    float x[IN_H];
    const float2* xr = (const float2*)(X + (size_t)v * IN_H);
    #pragma unroll
    for (int k = 0; k < IN_H / 2; ++k) {
        float2 c = xr[k];
        x[2 * k] = c.x; x[2 * k + 1] = c.y;
    }
    float dv = dinv[v];
    float* pr = Pp + (size_t)v * PSTRIDE;
    #pragma unroll
    for (int j = 0; j < OUT_H; ++j) {
        float s = 0.f;
        #pragma unroll
        for (int k = 0; k < IN_H; ++k) s += x[k] * sW[k * OUT_H + j];
        pr[j] = dv * s;
    }
    pr[11] = dv;            // fold dinv into the row (summed as "feature 11")
    pr[12] = 0.f; pr[13] = 0.f; pr[14] = 0.f; pr[15] = 0.f;
}

// ---------------- gather pass 1 (4 lanes/node): Z1' = dinv^2*(ÂP'), r ----------------
__global__ void k_gather1(const int* __restrict__ rowptr, const int* __restrict__ col,
                          const float* __restrict__ dinv, const float* __restrict__ Pp,
                          float* __restrict__ Z1p, float* __restrict__ r, int n) {
    int g = blockIdx.x * blockDim.x + threadIdx.x;
    int v = g >> 2;
    int lane = g & 3;
    if (v >= n) return;
    int beg = rowptr[v], end = rowptr[v + 1];
    float4 acc = make_float4(0.f, 0.f, 0.f, 0.f);
    const float4* P4 = (const float4*)Pp;
    int e = beg;
    for (; e + 1 < end; e += 2) {
        int s0 = col[e], s1 = col[e + 1];
        float4 a = P4[(size_t)s0 * 4 + lane];
        float4 b = P4[(size_t)s1 * 4 + lane];
        acc.x += a.x; acc.y += a.y; acc.z += a.z; acc.w += a.w;
        acc.x += b.x; acc.y += b.y; acc.z += b.z; acc.w += b.w;
    }
    if (e < end) {
        float4 a = P4[(size_t)col[e] * 4 + lane];
        acc.x += a.x; acc.y += a.y; acc.z += a.z; acc.w += a.w;
    }
    {   // self-loop
        float4 a = P4[(size_t)v * 4 + lane];
        acc.x += a.x; acc.y += a.y; acc.z += a.z; acc.w += a.w;
    }
    float dd = dinv[v];
    float s2 = dd * dd;
    float4 z = make_float4(s2 * acc.x, s2 * acc.y, s2 * acc.z, s2 * acc.w);
    ((float4*)Z1p)[(size_t)v * 4 + lane] = z;
    if (lane == 2) r[v] = dd * acc.w;   // acc.w = sum dinv[src] + dinv[v]
}

// ---------------- gather pass 2 (4 lanes/node): H2' = relu(dd*ÂZ1' + r*bb + b2) ----------------
__global__ void k_gather2(const int* __restrict__ rowptr, const int* __restrict__ col,
                          const float* __restrict__ dinv, const float* __restrict__ Z1p,
                          const float* __restrict__ r, const float* __restrict__ bbg,
                          const float* __restrict__ b2g, float* __restrict__ H2p, int n) {
    __shared__ float sbb[OUT_H + 1];
    __shared__ float sb2[OUT_H + 1];
    if (threadIdx.x < OUT_H) { sbb[threadIdx.x] = bbg[threadIdx.x]; sb2[threadIdx.x] = b2g[threadIdx.x]; }
    if (threadIdx.x == OUT_H) { sbb[OUT_H] = 0.f; sb2[OUT_H] = 0.f; }
    __syncthreads();
    int g = blockIdx.x * blockDim.x + threadIdx.x;
    int v = g >> 2;
    int lane = g & 3;
    if (v >= n || lane == 3) {
        // lane 3 contributes nothing (features 12..15 are pad) — but keep it
        // reading nothing to avoid divergent loads; just exit.
        if (v >= n || lane == 3) return;
    }
    int beg = rowptr[v], end = rowptr[v + 1];
    float4 acc = make_float4(0.f, 0.f, 0.f, 0.f);
    const float4* Z4 = (const float4*)Z1p;
    int e = beg;
    for (; e + 1 < end; e += 2) {
        int s0 = col[e], s1 = col[e + 1];
        float4 a = Z4[(size_t)s0 * 4 + lane];
        float4 b = Z4[(size_t)s1 * 4 + lane];
        acc.x += a.x; acc.y += a.y; acc.z += a.z; acc.w += a.w;
        acc.x += b.x; acc.y += b.y; acc.z += b.z; acc.w += b.w;
    }
    if (e < end) {
        float4 a = Z4[(size_t)col[e] * 4 + lane];
        acc.x += a.x; acc.y += a.y; acc.z += a.z; acc.w += a.w;
    }
    {
        float4 a = Z4[(size_t)v * 4 + lane];
        acc.x += a.x; acc.y += a.y; acc.z += a.z; acc.w += a.w;
    }
    float dd = dinv[v];
    float rv = r[v];
    float af[4] = {acc.x, acc.y, acc.z, acc.w};
    float h[4];
    #pragma unroll
    for (int c = 0; c < 4; ++c) {
        int f = 4 * lane + c;           // lane<=2 -> f<=11; f==11 maps to pad slot
        float tv = dd * af[c] + rv * sbb[f <= OUT_H ? f : OUT_H] + sb2[f <= OUT_H ? f : OUT_H];
        h[c] = tv > 0.f ? tv : 0.f;
    }
    if (lane == 2) h[3] = 0.f;          // pad slot 11
    ((float4*)(H2p + (size_t)v * HSTRIDE))[lane] = make_float4(h[0], h[1], h[2], h[3]);
}

// ---------------- dense: out = emb_a@Wc[:40] + H2'@Wc[40:] + bc (j-split, 4 lanes/node) ----------------
__global__ void k_dense(const float* __restrict__ emb_a, const float* __restrict__ H2p,
                        const float* __restrict__ Wc, const float* __restrict__ bc,
                        float* __restrict__ out, int n) {
    __shared__ float sWc[(NCLASS + OUT_H) * NCLASS];   // 51*40 = 2040
    __shared__ float sbc[NCLASS];
    for (int t = threadIdx.x; t < (NCLASS + OUT_H) * NCLASS; t += blockDim.x) sWc[t] = Wc[t];
    if (threadIdx.x < NCLASS) sbc[threadIdx.x] = bc[threadIdx.x];
    __syncthreads();
    int g = blockIdx.x * blockDim.x + threadIdx.x;
    int v = g >> 2;
    int lane = g & 3;
    if (v >= n) return;
    const int jb = 10 * lane;                 // this lane's 10 output columns
    float o[10];
    #pragma unroll
    for (int j = 0; j < 10; ++j) o[j] = sbc[jb + j];
    const float4* ea4 = (const float4*)(emb_a + (size_t)v * NCLASS);
    #pragma unroll
    for (int k4 = 0; k4 < NCLASS / 4; ++k4) {
        float4 a = ea4[k4];                   // same addr across 4 lanes -> broadcast
        const float* w0 = &sWc[(4 * k4 + 0) * NCLASS + jb];
        const float* w1 = &sWc[(4 * k4 + 1) * NCLASS + jb];
        const float* w2 = &sWc[(4 * k4 + 2) * NCLASS + jb];
        const float* w3 = &sWc[(4 * k4 + 3) * NCLASS + jb];
        #pragma unroll
        for (int j = 0; j < 10; ++j)
            o[j] += a.x * w0[j] + a.y * w1[j] + a.z * w2[j] + a.w * w3[j];
    }
    const float4* h4 = (const float4*)(H2p + (size_t)v * HSTRIDE);
    #pragma unroll
    for (int k4 = 0; k4 < 3; ++k4) {
        float4 a = h4[k4];
        float comp[4] = {a.x, a.y, a.z, a.w};
        #pragma unroll
        for (int c = 0; c < 4; ++c) {
            int f = 4 * k4 + c;
            if (f < OUT_H) {                  // f==11 is pad
                const float* w = &sWc[(NCLASS + f) * NCLASS + jb];
                #pragma unroll
                for (int j = 0; j < 10; ++j) o[j] += comp[c] * w[j];
            }
        }
    }
    float* orow = out + (size_t)v * NCLASS + jb;   // group writes 160B contiguous
    #pragma unroll
    for (int j2 = 0; j2 < 5; ++j2)
        *(float2*)(orow + 2 * j2) = make_float2(o[2 * j2], o[2 * j2 + 1]);
}

extern "C" void kernel_launch(void* const* d_in, const int* in_sizes, int n_in,
                              void* d_out, int out_size, void* d_ws, size_t ws_size,
                              hipStream_t stream) {
    const float* X     = (const float*)d_in[0];
    const int*   ei    = (const int*)d_in[1];
    const float* emb_a = (const float*)d_in[2];
    const float* W1    = (const float*)d_in[3];
    const float* b1    = (const float*)d_in[4];
    const float* W2    = (const float*)d_in[5];
    const float* b2    = (const float*)d_in[6];
    const float* Wc    = (const float*)d_in[7];
    const float* bc    = (const float*)d_in[8];
    float* out = (float*)d_out;

    char* ws = (char*)d_ws;
    size_t off = 0;
    auto alloc = [&](size_t nbytes) {
        void* p = (void*)(ws + off);
        off += ((nbytes + 255) / 256) * 256;
        return p;
    };
    // Aliasing: bh dead after k_bucket -> rvec. packed dead after k_sort -> Pp;
    // Pp dead after k_gather1 -> H2p (same region, 4.8MB < 6.4MB).
    char* bh_base = (char*)alloc((size_t)NB * NBLK * sizeof(int));        // 627 KB
    int*   bh     = (int*)bh_base;
    float* rvec   = (float*)bh_base;
    int*   btot   = (int*)  alloc(NB * sizeof(int));
    int*   bstart = (int*)  alloc((NB + 1) * sizeof(int));
    char* pk_base = (char*)alloc((size_t)N_EDGES * sizeof(unsigned int)); // 6.4 MB
    unsigned int* packed = (unsigned int*)pk_base;
    float* Pp     = (float*)pk_base;
    float* H2p    = (float*)pk_base;                                      // after gather1
    int*   col    = (int*)  alloc((size_t)N_EDGES * sizeof(int));
    int*   rowptr = (int*)  alloc((N_NODES + 1) * sizeof(int));
    float* dinv   = (float*)alloc(N_NODES * sizeof(float));
    float* W12    = (float*)alloc(IN_H * OUT_H * sizeof(float));
    float* bb     = (float*)alloc(OUT_H * sizeof(float));
    float* Z1p    = (float*)alloc((size_t)N_NODES * PSTRIDE * sizeof(float));

    const int B = 256;
    int gN  = (N_NODES + B - 1) / B;            // thread per node
    int gN4 = (N_NODES * 4 + B - 1) / B;        // 4 lanes per node

    k_hist   <<<NBLK, B, 0, stream>>>(ei + N_EDGES, bh, N_EDGES);
    k_btot   <<<NB, 256, 0, stream>>>(bh, btot);
    k_bstart <<<1, 64, 0, stream>>>(btot, bstart);
    k_boff   <<<NB, 1024, 0, stream>>>(bh, bstart);
    k_bucket <<<NBLK, B, 0, stream>>>(ei, bh, packed, N_EDGES);
    k_sort   <<<NB, 1024, 0, stream>>>(packed, bstart, col, rowptr, dinv);
    k_w12    <<<1, B, 0, stream>>>(W1, b1, W2, W12, bb);
    k_P      <<<gN, B, 0, stream>>>(X, W12, dinv, Pp, N_NODES);
    k_gather1<<<gN4, B, 0, stream>>>(rowptr, col, dinv, Pp, Z1p, rvec, N_NODES);
    k_gather2<<<gN4, B, 0, stream>>>(rowptr, col, dinv, Z1p, rvec, bb, b2, H2p, N_NODES);
    k_dense  <<<gN4, B, 0, stream>>>(emb_a, H2p, Wc, bc, out, N_NODES);
}

// Round 6
// 122.730 us; speedup vs baseline: 1.4616x; 1.1115x over previous
//
#include <hip/hip_runtime.h>

#define N_NODES 100000
#define N_EDGES 1600000
#define IN_H 18
#define OUT_H 11
#define NCLASS 40
#define NHID 256
#define PSTRIDE 16            // P'/Z1' rows: 11 feat + dinv + pad -> 64B (one line)

// ---- bucket-sort geometry ----
#define BBITS 9
#define BINS 512
#define NB 196                              // ceil(100000/512)
#define NBLK 800
#define CHUNK 2000                          // NBLK*CHUNK == N_EDGES; 2000%4==0
#define SRC_MASK 0x1FFFF

// ---------------- K1a: per-block bucket histogram (LDS atomics only) ----------------
__global__ void k_hist(const int* __restrict__ dst, int* __restrict__ bh, int E) {
    __shared__ int h[NB];
    int t = threadIdx.x;
    if (t < NB) h[t] = 0;
    __syncthreads();
    const int4* d4 = (const int4*)(dst + blockIdx.x * CHUNK);
    for (int i = t; i < CHUNK / 4; i += blockDim.x) {
        int4 w = d4[i];
        atomicAdd(&h[w.x >> BBITS], 1);
        atomicAdd(&h[w.y >> BBITS], 1);
        atomicAdd(&h[w.z >> BBITS], 1);
        atomicAdd(&h[w.w >> BBITS], 1);
    }
    __syncthreads();
    if (t < NB) bh[t * NBLK + blockIdx.x] = h[t];   // [bin][blk]
}

// ---------------- S1: bucket totals ----------------
__global__ void k_btot(const int* __restrict__ bh, int* __restrict__ btot) {
    __shared__ int s[256];
    int b = blockIdx.x, t = threadIdx.x;
    int sum = 0;
    for (int k = t; k < NBLK; k += 256) sum += bh[b * NBLK + k];
    s[t] = sum;
    __syncthreads();
    for (int off = 128; off > 0; off >>= 1) {
        if (t < off) s[t] += s[t + off];
        __syncthreads();
    }
    if (t == 0) btot[b] = s[0];
}

// ---------------- S2+S3 fused: per-(bin,blk) absolute offsets + bstart ----------------
// Each block redundantly scans btot (196 ints) in LDS to get its own bucket base,
// then scans its bh row. Eliminates the serial k_bstart kernel.
__global__ __launch_bounds__(1024) void k_boff(int* __restrict__ bh,
                                               const int* __restrict__ btot,
                                               int* __restrict__ bstart) {
    __shared__ int s0[1024], s1[1024];
    __shared__ int bt0[256], bt1[256];
    int b = blockIdx.x, t = threadIdx.x;
    if (t < 256) bt0[t] = (t < NB) ? btot[t] : 0;
    __syncthreads();
    int* c0 = bt0; int* c1 = bt1;
    for (int off = 1; off < 256; off <<= 1) {
        if (t < 256) c1[t] = c0[t] + ((t >= off) ? c0[t - off] : 0);
        __syncthreads();
        int* tmp = c0; c0 = c1; c1 = tmp;
    }
    int base = c0[b] - btot[b];              // exclusive prefix = bucket base
    if (t == 0) {
        bstart[b] = base;
        if (b == 0) bstart[NB] = N_EDGES;
    }
    int v = (t < NBLK) ? bh[b * NBLK + t] : 0;
    s0[t] = v;
    __syncthreads();
    int* c = s0; int* n = s1;
    for (int off = 1; off < 1024; off <<= 1) {
        n[t] = c[t] + ((t >= off) ? c[t - off] : 0);
        __syncthreads();
        int* tmp = c; c = n; n = tmp;
    }
    if (t < NBLK) bh[b * NBLK + t] = c[t] - v + base;
}

// ---------------- K1c: scatter edges into buckets (LDS cursors) ----------------
__global__ void k_bucket(const int* __restrict__ ei, const int* __restrict__ bh,
                         unsigned int* __restrict__ packed, int E) {
    __shared__ int cur[NB];
    int t = threadIdx.x;
    if (t < NB) cur[t] = bh[t * NBLK + blockIdx.x];
    __syncthreads();
    int base = blockIdx.x * CHUNK;
    const int4* s4 = (const int4*)(ei + base);
    const int4* d4 = (const int4*)(ei + E + base);
    for (int i = t; i < CHUNK / 4; i += blockDim.x) {
        int4 s = s4[i];
        int4 d = d4[i];
        int sl;
        sl = atomicAdd(&cur[d.x >> BBITS], 1);
        packed[sl] = ((unsigned)(d.x & (BINS - 1)) << 17) | (unsigned)s.x;
        sl = atomicAdd(&cur[d.y >> BBITS], 1);
        packed[sl] = ((unsigned)(d.y & (BINS - 1)) << 17) | (unsigned)s.y;
        sl = atomicAdd(&cur[d.z >> BBITS], 1);
        packed[sl] = ((unsigned)(d.z & (BINS - 1)) << 17) | (unsigned)s.z;
        sl = atomicAdd(&cur[d.w >> BBITS], 1);
        packed[sl] = ((unsigned)(d.w & (BINS - 1)) << 17) | (unsigned)s.w;
    }
}

// ---------------- W12 = W1 @ W2, bb = b1 @ W2 (one block) ----------------
__global__ void k_w12(const float* __restrict__ W1, const float* __restrict__ b1,
                      const float* __restrict__ W2,
                      float* __restrict__ W12, float* __restrict__ bb) {
    int t = threadIdx.x;
    if (t < IN_H * OUT_H) {
        int i = t / OUT_H, j = t % OUT_H;
        float s = 0.f;
        for (int k = 0; k < NHID; ++k) s += W1[i * NHID + k] * W2[k * OUT_H + j];
        W12[t] = s;
    } else if (t < IN_H * OUT_H + OUT_H) {
        int j = t - IN_H * OUT_H;
        float s = 0.f;
        for (int k = 0; k < NHID; ++k) s += b1[k] * W2[k * OUT_H + j];
        bb[j] = s;
    }
}

// ---------------- K2: per-bucket counting sort -> col, rowptr, dinv, P' ----------------
// Fused P': thread t<512 owns node (b<<9)+t, already has its degree in hist[t];
// computes P'row = [dinv*(X@W12) (11), dinv, pad] straight to global.
__global__ __launch_bounds__(1024)
void k_sort(const unsigned int* __restrict__ packed, const int* __restrict__ bstart,
            const float* __restrict__ X, const float* __restrict__ W12g,
            int* __restrict__ col, int* __restrict__ rowptr,
            float* __restrict__ dinv, float* __restrict__ Pp) {
    __shared__ int hist[BINS];
    __shared__ int s0[BINS], s1[BINS];
    __shared__ int cur[BINS];
    __shared__ float sW[IN_H * OUT_H];
    int b = blockIdx.x, t = threadIdx.x;
    int beg = bstart[b], end = bstart[b + 1];
    if (t < BINS) hist[t] = 0;
    if (t >= BINS && t < BINS + IN_H * OUT_H) sW[t - BINS] = W12g[t - BINS];
    __syncthreads();
    for (int i = beg + t; i < end; i += blockDim.x)
        atomicAdd(&hist[packed[i] >> 17], 1);
    __syncthreads();
    if (t < BINS) s0[t] = hist[t];
    __syncthreads();
    int* c = s0; int* n = s1;
    for (int off = 1; off < BINS; off <<= 1) {
        if (t < BINS) n[t] = c[t] + ((t >= off) ? c[t - off] : 0);
        __syncthreads();
        int* tmp = c; c = n; n = tmp;
    }
    if (t < BINS) {
        int excl = c[t] - hist[t];
        int gbase = beg + excl;
        cur[t] = gbase;
        int node = (b << BBITS) + t;
        if (node <= N_NODES) rowptr[node] = gbase;
        if (node < N_NODES)  dinv[node] = rsqrtf((float)(hist[t] + 1));
    }
    __syncthreads();
    for (int i = beg + t; i < end; i += blockDim.x) {
        unsigned p = packed[i];
        int slot = atomicAdd(&cur[p >> 17], 1);
        col[slot] = (int)(p & SRC_MASK);
    }
    // ---- fused P' ----
    int node = (b << BBITS) + t;
    if (t < BINS && node < N_NODES) {
        float dv = rsqrtf((float)(hist[t] + 1));
        float x[IN_H];
        const float2* xr = (const float2*)(X + (size_t)node * IN_H);
        #pragma unroll
        for (int k = 0; k < IN_H / 2; ++k) {
            float2 cc = xr[k];
            x[2 * k] = cc.x; x[2 * k + 1] = cc.y;
        }
        float* pr = Pp + (size_t)node * PSTRIDE;
        #pragma unroll
        for (int j = 0; j < OUT_H; ++j) {
            float s = 0.f;
            #pragma unroll
            for (int k = 0; k < IN_H; ++k) s += x[k] * sW[k * OUT_H + j];
            pr[j] = dv * s;
        }
        pr[11] = dv;   // dinv folded in as "feature 11"
        pr[12] = 0.f; pr[13] = 0.f; pr[14] = 0.f; pr[15] = 0.f;
    }
}

// ---------------- gather pass 1 (4 lanes/node, unroll 4): Z1' = dinv^2*(ÂP'), r ----------------
__global__ void k_gather1(const int* __restrict__ rowptr, const int* __restrict__ col,
                          const float* __restrict__ dinv, const float* __restrict__ Pp,
                          float* __restrict__ Z1p, float* __restrict__ r, int n) {
    int g = blockIdx.x * blockDim.x + threadIdx.x;
    int v = g >> 2;
    int lane = g & 3;
    if (v >= n) return;
    int beg = rowptr[v], end = rowptr[v + 1];
    float4 acc = make_float4(0.f, 0.f, 0.f, 0.f);
    const float4* P4 = (const float4*)Pp;
    int e = beg;
    for (; e + 3 < end; e += 4) {
        int i0 = col[e], i1 = col[e + 1], i2 = col[e + 2], i3 = col[e + 3];
        float4 a0 = P4[(size_t)i0 * 4 + lane];
        float4 a1 = P4[(size_t)i1 * 4 + lane];
        float4 a2 = P4[(size_t)i2 * 4 + lane];
        float4 a3 = P4[(size_t)i3 * 4 + lane];
        acc.x += a0.x + a1.x + a2.x + a3.x;
        acc.y += a0.y + a1.y + a2.y + a3.y;
        acc.z += a0.z + a1.z + a2.z + a3.z;
        acc.w += a0.w + a1.w + a2.w + a3.w;
    }
    for (; e < end; ++e) {
        float4 a = P4[(size_t)col[e] * 4 + lane];
        acc.x += a.x; acc.y += a.y; acc.z += a.z; acc.w += a.w;
    }
    {   // self-loop
        float4 a = P4[(size_t)v * 4 + lane];
        acc.x += a.x; acc.y += a.y; acc.z += a.z; acc.w += a.w;
    }
    float dd = dinv[v];
    float s2 = dd * dd;
    ((float4*)Z1p)[(size_t)v * 4 + lane] =
        make_float4(s2 * acc.x, s2 * acc.y, s2 * acc.z, s2 * acc.w);
    if (lane == 2) r[v] = dd * acc.w;   // acc.w(lane2) = sum dinv[src] + dinv[v]
}

// ---------------- gather pass 2 FUSED with dense epilogue ----------------
// 4 lanes/node: gather Z1' (validated pattern), h via relu, width-4 shfl broadcast,
// then j-split matmul (10 output cols/lane) with contiguous 40B/lane writes.
__global__ void k_g2d(const int* __restrict__ rowptr, const int* __restrict__ col,
                      const float* __restrict__ dinv, const float* __restrict__ Z1p,
                      const float* __restrict__ r, const float* __restrict__ bbg,
                      const float* __restrict__ b2g, const float* __restrict__ emb_a,
                      const float* __restrict__ Wc, const float* __restrict__ bc,
                      float* __restrict__ out, int n) {
    __shared__ float sWc[(NCLASS + OUT_H) * NCLASS];   // 51*40 = 2040
    __shared__ float sbc[NCLASS];
    __shared__ float sbb[16];
    __shared__ float sb2[16];
    for (int t = threadIdx.x; t < (NCLASS + OUT_H) * NCLASS; t += blockDim.x) sWc[t] = Wc[t];
    if (threadIdx.x < NCLASS) sbc[threadIdx.x] = bc[threadIdx.x];
    if (threadIdx.x < 16) {
        sbb[threadIdx.x] = (threadIdx.x < OUT_H) ? bbg[threadIdx.x] : 0.f;
        sb2[threadIdx.x] = (threadIdx.x < OUT_H) ? b2g[threadIdx.x] : 0.f;
    }
    __syncthreads();
    int g = blockIdx.x * blockDim.x + threadIdx.x;
    int v = g >> 2;
    int lane = g & 3;
    if (v >= n) return;
    int beg = rowptr[v], end = rowptr[v + 1];
    float4 acc = make_float4(0.f, 0.f, 0.f, 0.f);
    const float4* Z4 = (const float4*)Z1p;
    int e = beg;
    for (; e + 3 < end; e += 4) {
        int i0 = col[e], i1 = col[e + 1], i2 = col[e + 2], i3 = col[e + 3];
        float4 a0 = Z4[(size_t)i0 * 4 + lane];
        float4 a1 = Z4[(size_t)i1 * 4 + lane];
        float4 a2 = Z4[(size_t)i2 * 4 + lane];
        float4 a3 = Z4[(size_t)i3 * 4 + lane];
        acc.x += a0.x + a1.x + a2.x + a3.x;
        acc.y += a0.y + a1.y + a2.y + a3.y;
        acc.z += a0.z + a1.z + a2.z + a3.z;
        acc.w += a0.w + a1.w + a2.w + a3.w;
    }
    for (; e < end; ++e) {
        float4 a = Z4[(size_t)col[e] * 4 + lane];
        acc.x += a.x; acc.y += a.y; acc.z += a.z; acc.w += a.w;
    }
    {
        float4 a = Z4[(size_t)v * 4 + lane];
        acc.x += a.x; acc.y += a.y; acc.z += a.z; acc.w += a.w;
    }
    float dd = dinv[v];
    float rv = r[v];
    float af[4] = {acc.x, acc.y, acc.z, acc.w};
    float hloc[4];
    #pragma unroll
    for (int c = 0; c < 4; ++c) {
        int f = 4 * lane + c;                 // f in [0,15]; >=11 is pad (zero biases)
        float tv = dd * af[c] + rv * sbb[f] + sb2[f];
        hloc[c] = tv > 0.f ? tv : 0.f;
    }
    // broadcast the 11 h features across the 4-lane group (lane f>>2 owns f)
    float hall[OUT_H];
    #pragma unroll
    for (int f = 0; f < OUT_H; ++f)
        hall[f] = __shfl(hloc[f & 3], f >> 2, 4);
    // j-split dense: this lane owns output columns [10*lane, 10*lane+10)
    const int jb = 10 * lane;
    float o[10];
    #pragma unroll
    for (int j = 0; j < 10; ++j) o[j] = sbc[jb + j];
    const float4* ea4 = (const float4*)(emb_a + (size_t)v * NCLASS);
    #pragma unroll
    for (int k4 = 0; k4 < NCLASS / 4; ++k4) {
        float4 a = ea4[k4];                   // same addr across lanes -> broadcast
        const float* w0 = &sWc[(4 * k4 + 0) * NCLASS + jb];
        const float* w1 = &sWc[(4 * k4 + 1) * NCLASS + jb];
        const float* w2 = &sWc[(4 * k4 + 2) * NCLASS + jb];
        const float* w3 = &sWc[(4 * k4 + 3) * NCLASS + jb];
        #pragma unroll
        for (int j = 0; j < 10; ++j)
            o[j] += a.x * w0[j] + a.y * w1[j] + a.z * w2[j] + a.w * w3[j];
    }
    #pragma unroll
    for (int f = 0; f < OUT_H; ++f) {
        const float* w = &sWc[(NCLASS + f) * NCLASS + jb];
        float hv = hall[f];
        #pragma unroll
        for (int j = 0; j < 10; ++j) o[j] += hv * w[j];
    }
    float* orow = out + (size_t)v * NCLASS + jb;   // group writes 160B contiguous
    #pragma unroll
    for (int j2 = 0; j2 < 5; ++j2)
        *(float2*)(orow + 2 * j2) = make_float2(o[2 * j2], o[2 * j2 + 1]);
}

extern "C" void kernel_launch(void* const* d_in, const int* in_sizes, int n_in,
                              void* d_out, int out_size, void* d_ws, size_t ws_size,
                              hipStream_t stream) {
    const float* X     = (const float*)d_in[0];
    const int*   ei    = (const int*)d_in[1];
    const float* emb_a = (const float*)d_in[2];
    const float* W1    = (const float*)d_in[3];
    const float* b1    = (const float*)d_in[4];
    const float* W2    = (const float*)d_in[5];
    const float* b2    = (const float*)d_in[6];
    const float* Wc    = (const float*)d_in[7];
    const float* bc    = (const float*)d_in[8];
    float* out = (float*)d_out;

    char* ws = (char*)d_ws;
    size_t off = 0;
    auto alloc = [&](size_t nbytes) {
        void* p = (void*)(ws + off);
        off += ((nbytes + 255) / 256) * 256;
        return p;
    };
    // bh dead after k_bucket -> rvec aliases it. packed is READ by k_sort while
    // Pp is WRITTEN -> Pp gets its own region (no aliasing with packed anymore).
    char* bh_base = (char*)alloc((size_t)NB * NBLK * sizeof(int));        // 627 KB
    int*   bh     = (int*)bh_base;
    float* rvec   = (float*)bh_base;
    int*   btot   = (int*)  alloc(NB * sizeof(int));
    int*   bstart = (int*)  alloc((NB + 1) * sizeof(int));
    unsigned int* packed = (unsigned int*)alloc((size_t)N_EDGES * sizeof(unsigned int));
    int*   col    = (int*)  alloc((size_t)N_EDGES * sizeof(int));
    int*   rowptr = (int*)  alloc((N_NODES + 1) * sizeof(int));
    float* dinv   = (float*)alloc(N_NODES * sizeof(float));
    float* W12    = (float*)alloc(IN_H * OUT_H * sizeof(float));
    float* bb     = (float*)alloc(OUT_H * sizeof(float));
    float* Pp     = (float*)alloc((size_t)N_NODES * PSTRIDE * sizeof(float));
    float* Z1p    = (float*)alloc((size_t)N_NODES * PSTRIDE * sizeof(float));

    const int B = 256;
    int gN4 = (N_NODES * 4 + B - 1) / B;        // 4 lanes per node

    k_w12    <<<1, B, 0, stream>>>(W1, b1, W2, W12, bb);
    k_hist   <<<NBLK, B, 0, stream>>>(ei + N_EDGES, bh, N_EDGES);
    k_btot   <<<NB, 256, 0, stream>>>(bh, btot);
    k_boff   <<<NB, 1024, 0, stream>>>(bh, btot, bstart);
    k_bucket <<<NBLK, B, 0, stream>>>(ei, bh, packed, N_EDGES);
    k_sort   <<<NB, 1024, 0, stream>>>(packed, bstart, X, W12, col, rowptr, dinv, Pp);
    k_gather1<<<gN4, B, 0, stream>>>(rowptr, col, dinv, Pp, Z1p, rvec, N_NODES);
    k_g2d    <<<gN4, B, 0, stream>>>(rowptr, col, dinv, Z1p, rvec, bb, b2, emb_a,
                                     Wc, bc, out, N_NODES);
}

// Round 7
// 112.571 us; speedup vs baseline: 1.5935x; 1.0902x over previous
//
#include <hip/hip_runtime.h>

#define N_NODES 100000
#define N_EDGES 1600000
#define IN_H 18
#define OUT_H 11
#define NCLASS 40
#define NHID 256
// P'/Z1' rows: 16 bf16 elems = 32B = one 32B-aligned half-line.
// elems 0..10 features, 11 = dinv (P') / unused (Z1'), 12..15 pad.

// ---- bucket-sort geometry ----
#define BBITS 9
#define BINS 512
#define NB 196                              // ceil(100000/512)
#define NBLK 800
#define CHUNK 2000                          // NBLK*CHUNK == N_EDGES; 2000%4==0
#define SRC_MASK 0x1FFFF

// ---- bf16 helpers (storage-only quantization, f32 accumulate) ----
__device__ __forceinline__ float bflo(unsigned u) { return __uint_as_float(u << 16); }
__device__ __forceinline__ float bfhi(unsigned u) { return __uint_as_float(u & 0xFFFF0000u); }
__device__ __forceinline__ unsigned bfr(float x) {             // f32 -> bf16 bits, RNE
    unsigned u = __float_as_uint(x);
    return (u + 0x7FFFu + ((u >> 16) & 1u)) >> 16;
}
__device__ __forceinline__ unsigned bfpack(float a, float b) { return bfr(a) | (bfr(b) << 16); }
__device__ __forceinline__ float4 bfunpack4(uint2 w) {
    return make_float4(bflo(w.x), bfhi(w.x), bflo(w.y), bfhi(w.y));
}

// ---------------- K1a: per-block bucket histogram (LDS atomics only) ----------------
__global__ void k_hist(const int* __restrict__ dst, int* __restrict__ bh, int E) {
    __shared__ int h[NB];
    int t = threadIdx.x;
    if (t < NB) h[t] = 0;
    __syncthreads();
    const int4* d4 = (const int4*)(dst + blockIdx.x * CHUNK);
    for (int i = t; i < CHUNK / 4; i += blockDim.x) {
        int4 w = d4[i];
        atomicAdd(&h[w.x >> BBITS], 1);
        atomicAdd(&h[w.y >> BBITS], 1);
        atomicAdd(&h[w.z >> BBITS], 1);
        atomicAdd(&h[w.w >> BBITS], 1);
    }
    __syncthreads();
    if (t < NB) bh[t * NBLK + blockIdx.x] = h[t];   // [bin][blk]
}

// ---------------- S1: bucket totals ----------------
__global__ void k_btot(const int* __restrict__ bh, int* __restrict__ btot) {
    __shared__ int s[256];
    int b = blockIdx.x, t = threadIdx.x;
    int sum = 0;
    for (int k = t; k < NBLK; k += 256) sum += bh[b * NBLK + k];
    s[t] = sum;
    __syncthreads();
    for (int off = 128; off > 0; off >>= 1) {
        if (t < off) s[t] += s[t + off];
        __syncthreads();
    }
    if (t == 0) btot[b] = s[0];
}

// ---------------- S2+S3 fused: per-(bin,blk) absolute offsets + bstart ----------------
__global__ __launch_bounds__(1024) void k_boff(int* __restrict__ bh,
                                               const int* __restrict__ btot,
                                               int* __restrict__ bstart) {
    __shared__ int s0[1024], s1[1024];
    __shared__ int bt0[256], bt1[256];
    int b = blockIdx.x, t = threadIdx.x;
    if (t < 256) bt0[t] = (t < NB) ? btot[t] : 0;
    __syncthreads();
    int* c0 = bt0; int* c1 = bt1;
    for (int off = 1; off < 256; off <<= 1) {
        if (t < 256) c1[t] = c0[t] + ((t >= off) ? c0[t - off] : 0);
        __syncthreads();
        int* tmp = c0; c0 = c1; c1 = tmp;
    }
    int base = c0[b] - btot[b];              // exclusive prefix = bucket base
    if (t == 0) {
        bstart[b] = base;
        if (b == 0) bstart[NB] = N_EDGES;
    }
    int v = (t < NBLK) ? bh[b * NBLK + t] : 0;
    s0[t] = v;
    __syncthreads();
    int* c = s0; int* n = s1;
    for (int off = 1; off < 1024; off <<= 1) {
        n[t] = c[t] + ((t >= off) ? c[t - off] : 0);
        __syncthreads();
        int* tmp = c; c = n; n = tmp;
    }
    if (t < NBLK) bh[b * NBLK + t] = c[t] - v + base;
}

// ---------------- K1c: scatter edges into buckets (LDS cursors) ----------------
__global__ void k_bucket(const int* __restrict__ ei, const int* __restrict__ bh,
                         unsigned int* __restrict__ packed, int E) {
    __shared__ int cur[NB];
    int t = threadIdx.x;
    if (t < NB) cur[t] = bh[t * NBLK + blockIdx.x];
    __syncthreads();
    int base = blockIdx.x * CHUNK;
    const int4* s4 = (const int4*)(ei + base);
    const int4* d4 = (const int4*)(ei + E + base);
    for (int i = t; i < CHUNK / 4; i += blockDim.x) {
        int4 s = s4[i];
        int4 d = d4[i];
        int sl;
        sl = atomicAdd(&cur[d.x >> BBITS], 1);
        packed[sl] = ((unsigned)(d.x & (BINS - 1)) << 17) | (unsigned)s.x;
        sl = atomicAdd(&cur[d.y >> BBITS], 1);
        packed[sl] = ((unsigned)(d.y & (BINS - 1)) << 17) | (unsigned)s.y;
        sl = atomicAdd(&cur[d.z >> BBITS], 1);
        packed[sl] = ((unsigned)(d.z & (BINS - 1)) << 17) | (unsigned)s.z;
        sl = atomicAdd(&cur[d.w >> BBITS], 1);
        packed[sl] = ((unsigned)(d.w & (BINS - 1)) << 17) | (unsigned)s.w;
    }
}

// ---------------- W12 = W1 @ W2, bb = b1 @ W2 (one block) ----------------
__global__ void k_w12(const float* __restrict__ W1, const float* __restrict__ b1,
                      const float* __restrict__ W2,
                      float* __restrict__ W12, float* __restrict__ bb) {
    int t = threadIdx.x;
    if (t < IN_H * OUT_H) {
        int i = t / OUT_H, j = t % OUT_H;
        float s = 0.f;
        for (int k = 0; k < NHID; ++k) s += W1[i * NHID + k] * W2[k * OUT_H + j];
        W12[t] = s;
    } else if (t < IN_H * OUT_H + OUT_H) {
        int j = t - IN_H * OUT_H;
        float s = 0.f;
        for (int k = 0; k < NHID; ++k) s += b1[k] * W2[k * OUT_H + j];
        bb[j] = s;
    }
}

// ---------------- K2: per-bucket counting sort -> col, rowptr, dinv, P'(bf16) ----------------
__global__ __launch_bounds__(1024)
void k_sort(const unsigned int* __restrict__ packed, const int* __restrict__ bstart,
            const float* __restrict__ X, const float* __restrict__ W12g,
            int* __restrict__ col, int* __restrict__ rowptr,
            float* __restrict__ dinv, unsigned int* __restrict__ Pp) {
    __shared__ int hist[BINS];
    __shared__ int s0[BINS], s1[BINS];
    __shared__ int cur[BINS];
    __shared__ float sW[IN_H * OUT_H];
    int b = blockIdx.x, t = threadIdx.x;
    int beg = bstart[b], end = bstart[b + 1];
    if (t < BINS) hist[t] = 0;
    if (t >= BINS && t < BINS + IN_H * OUT_H) sW[t - BINS] = W12g[t - BINS];
    __syncthreads();
    for (int i = beg + t; i < end; i += blockDim.x)
        atomicAdd(&hist[packed[i] >> 17], 1);
    __syncthreads();
    if (t < BINS) s0[t] = hist[t];
    __syncthreads();
    int* c = s0; int* n = s1;
    for (int off = 1; off < BINS; off <<= 1) {
        if (t < BINS) n[t] = c[t] + ((t >= off) ? c[t - off] : 0);
        __syncthreads();
        int* tmp = c; c = n; n = tmp;
    }
    if (t < BINS) {
        int excl = c[t] - hist[t];
        int gbase = beg + excl;
        cur[t] = gbase;
        int node = (b << BBITS) + t;
        if (node <= N_NODES) rowptr[node] = gbase;
        if (node < N_NODES)  dinv[node] = rsqrtf((float)(hist[t] + 1));
    }
    __syncthreads();
    for (int i = beg + t; i < end; i += blockDim.x) {
        unsigned p = packed[i];
        int slot = atomicAdd(&cur[p >> 17], 1);
        col[slot] = (int)(p & SRC_MASK);
    }
    // ---- fused P' (bf16 rows, 32B) ----
    int node = (b << BBITS) + t;
    if (t < BINS && node < N_NODES) {
        float dv = rsqrtf((float)(hist[t] + 1));
        float x[IN_H];
        const float2* xr = (const float2*)(X + (size_t)node * IN_H);
        #pragma unroll
        for (int k = 0; k < IN_H / 2; ++k) {
            float2 cc = xr[k];
            x[2 * k] = cc.x; x[2 * k + 1] = cc.y;
        }
        float pf[12];
        #pragma unroll
        for (int j = 0; j < OUT_H; ++j) {
            float s = 0.f;
            #pragma unroll
            for (int k = 0; k < IN_H; ++k) s += x[k] * sW[k * OUT_H + j];
            pf[j] = dv * s;
        }
        pf[11] = dv;                          // dinv folded in as "feature 11"
        uint4* pw = (uint4*)(Pp + (size_t)node * 8);
        pw[0] = make_uint4(bfpack(pf[0], pf[1]), bfpack(pf[2], pf[3]),
                           bfpack(pf[4], pf[5]), bfpack(pf[6], pf[7]));
        pw[1] = make_uint4(bfpack(pf[8], pf[9]), bfpack(pf[10], pf[11]), 0u, 0u);
    }
}

// ---------------- gather pass 1 (4 lanes/node, unroll 4, bf16 rows) ----------------
__global__ void k_gather1(const int* __restrict__ rowptr, const int* __restrict__ col,
                          const float* __restrict__ dinv, const unsigned int* __restrict__ Pp,
                          unsigned int* __restrict__ Z1p, float* __restrict__ r, int n) {
    int g = blockIdx.x * blockDim.x + threadIdx.x;
    int v = g >> 2;
    int lane = g & 3;
    if (v >= n) return;
    int beg = rowptr[v], end = rowptr[v + 1];
    float4 acc = make_float4(0.f, 0.f, 0.f, 0.f);
    const uint2* P2 = (const uint2*)Pp;       // 4 uint2 per 32B row
    int e = beg;
    for (; e + 3 < end; e += 4) {
        int i0 = col[e], i1 = col[e + 1], i2 = col[e + 2], i3 = col[e + 3];
        uint2 w0 = P2[(size_t)i0 * 4 + lane];
        uint2 w1 = P2[(size_t)i1 * 4 + lane];
        uint2 w2 = P2[(size_t)i2 * 4 + lane];
        uint2 w3 = P2[(size_t)i3 * 4 + lane];
        float4 a0 = bfunpack4(w0), a1 = bfunpack4(w1), a2 = bfunpack4(w2), a3 = bfunpack4(w3);
        acc.x += a0.x + a1.x + a2.x + a3.x;
        acc.y += a0.y + a1.y + a2.y + a3.y;
        acc.z += a0.z + a1.z + a2.z + a3.z;
        acc.w += a0.w + a1.w + a2.w + a3.w;
    }
    for (; e < end; ++e) {
        float4 a = bfunpack4(P2[(size_t)col[e] * 4 + lane]);
        acc.x += a.x; acc.y += a.y; acc.z += a.z; acc.w += a.w;
    }
    {   // self-loop
        float4 a = bfunpack4(P2[(size_t)v * 4 + lane]);
        acc.x += a.x; acc.y += a.y; acc.z += a.z; acc.w += a.w;
    }
    float dd = dinv[v];
    float s2 = dd * dd;
    ((uint2*)Z1p)[(size_t)v * 4 + lane] =
        make_uint2(bfpack(s2 * acc.x, s2 * acc.y), bfpack(s2 * acc.z, s2 * acc.w));
    if (lane == 2) r[v] = dd * acc.w;   // acc.w(lane2) = sum dinv[src] + dinv[v]
}

// ---------------- gather pass 2 FUSED with dense epilogue (bf16 rows) ----------------
__global__ void k_g2d(const int* __restrict__ rowptr, const int* __restrict__ col,
                      const float* __restrict__ dinv, const unsigned int* __restrict__ Z1p,
                      const float* __restrict__ r, const float* __restrict__ bbg,
                      const float* __restrict__ b2g, const float* __restrict__ emb_a,
                      const float* __restrict__ Wc, const float* __restrict__ bc,
                      float* __restrict__ out, int n) {
    __shared__ float sWc[(NCLASS + OUT_H) * NCLASS];   // 51*40 = 2040
    __shared__ float sbc[NCLASS];
    __shared__ float sbb[16];
    __shared__ float sb2[16];
    for (int t = threadIdx.x; t < (NCLASS + OUT_H) * NCLASS; t += blockDim.x) sWc[t] = Wc[t];
    if (threadIdx.x < NCLASS) sbc[threadIdx.x] = bc[threadIdx.x];
    if (threadIdx.x < 16) {
        sbb[threadIdx.x] = (threadIdx.x < OUT_H) ? bbg[threadIdx.x] : 0.f;
        sb2[threadIdx.x] = (threadIdx.x < OUT_H) ? b2g[threadIdx.x] : 0.f;
    }
    __syncthreads();
    int g = blockIdx.x * blockDim.x + threadIdx.x;
    int v = g >> 2;
    int lane = g & 3;
    if (v >= n) return;
    int beg = rowptr[v], end = rowptr[v + 1];
    float4 acc = make_float4(0.f, 0.f, 0.f, 0.f);
    const uint2* Z2 = (const uint2*)Z1p;
    int e = beg;
    for (; e + 3 < end; e += 4) {
        int i0 = col[e], i1 = col[e + 1], i2 = col[e + 2], i3 = col[e + 3];
        uint2 w0 = Z2[(size_t)i0 * 4 + lane];
        uint2 w1 = Z2[(size_t)i1 * 4 + lane];
        uint2 w2 = Z2[(size_t)i2 * 4 + lane];
        uint2 w3 = Z2[(size_t)i3 * 4 + lane];
        float4 a0 = bfunpack4(w0), a1 = bfunpack4(w1), a2 = bfunpack4(w2), a3 = bfunpack4(w3);
        acc.x += a0.x + a1.x + a2.x + a3.x;
        acc.y += a0.y + a1.y + a2.y + a3.y;
        acc.z += a0.z + a1.z + a2.z + a3.z;
        acc.w += a0.w + a1.w + a2.w + a3.w;
    }
    for (; e < end; ++e) {
        float4 a = bfunpack4(Z2[(size_t)col[e] * 4 + lane]);
        acc.x += a.x; acc.y += a.y; acc.z += a.z; acc.w += a.w;
    }
    {
        float4 a = bfunpack4(Z2[(size_t)v * 4 + lane]);
        acc.x += a.x; acc.y += a.y; acc.z += a.z; acc.w += a.w;
    }
    float dd = dinv[v];
    float rv = r[v];
    float af[4] = {acc.x, acc.y, acc.z, acc.w};
    float hloc[4];
    #pragma unroll
    for (int c = 0; c < 4; ++c) {
        int f = 4 * lane + c;                 // f in [0,15]; >=11 is pad (zero biases)
        float tv = dd * af[c] + rv * sbb[f] + sb2[f];
        hloc[c] = tv > 0.f ? tv : 0.f;
    }
    // broadcast the 11 h features across the 4-lane group (lane f>>2 owns f)
    float hall[OUT_H];
    #pragma unroll
    for (int f = 0; f < OUT_H; ++f)
        hall[f] = __shfl(hloc[f & 3], f >> 2, 4);
    // j-split dense: this lane owns output columns [10*lane, 10*lane+10)
    const int jb = 10 * lane;
    float o[10];
    #pragma unroll
    for (int j = 0; j < 10; ++j) o[j] = sbc[jb + j];
    const float4* ea4 = (const float4*)(emb_a + (size_t)v * NCLASS);
    #pragma unroll
    for (int k4 = 0; k4 < NCLASS / 4; ++k4) {
        float4 a = ea4[k4];                   // same addr across lanes -> broadcast
        const float* w0 = &sWc[(4 * k4 + 0) * NCLASS + jb];
        const float* w1 = &sWc[(4 * k4 + 1) * NCLASS + jb];
        const float* w2 = &sWc[(4 * k4 + 2) * NCLASS + jb];
        const float* w3 = &sWc[(4 * k4 + 3) * NCLASS + jb];
        #pragma unroll
        for (int j = 0; j < 10; ++j)
            o[j] += a.x * w0[j] + a.y * w1[j] + a.z * w2[j] + a.w * w3[j];
    }
    #pragma unroll
    for (int f = 0; f < OUT_H; ++f) {
        const float* w = &sWc[(NCLASS + f) * NCLASS + jb];
        float hv = hall[f];
        #pragma unroll
        for (int j = 0; j < 10; ++j) o[j] += hv * w[j];
    }
    float* orow = out + (size_t)v * NCLASS + jb;   // group writes 160B contiguous
    #pragma unroll
    for (int j2 = 0; j2 < 5; ++j2)
        *(float2*)(orow + 2 * j2) = make_float2(o[2 * j2], o[2 * j2 + 1]);
}

extern "C" void kernel_launch(void* const* d_in, const int* in_sizes, int n_in,
                              void* d_out, int out_size, void* d_ws, size_t ws_size,
                              hipStream_t stream) {
    const float* X     = (const float*)d_in[0];
    const int*   ei    = (const int*)d_in[1];
    const float* emb_a = (const float*)d_in[2];
    const float* W1    = (const float*)d_in[3];
    const float* b1    = (const float*)d_in[4];
    const float* W2    = (const float*)d_in[5];
    const float* b2    = (const float*)d_in[6];
    const float* Wc    = (const float*)d_in[7];
    const float* bc    = (const float*)d_in[8];
    float* out = (float*)d_out;

    char* ws = (char*)d_ws;
    size_t off = 0;
    auto alloc = [&](size_t nbytes) {
        void* p = (void*)(ws + off);
        off += ((nbytes + 255) / 256) * 256;
        return p;
    };
    // bh dead after k_bucket -> rvec aliases it.
    char* bh_base = (char*)alloc((size_t)NB * NBLK * sizeof(int));        // 627 KB
    int*   bh     = (int*)bh_base;
    float* rvec   = (float*)bh_base;
    int*   btot   = (int*)  alloc(NB * sizeof(int));
    int*   bstart = (int*)  alloc((NB + 1) * sizeof(int));
    unsigned int* packed = (unsigned int*)alloc((size_t)N_EDGES * sizeof(unsigned int));
    int*   col    = (int*)  alloc((size_t)N_EDGES * sizeof(int));
    int*   rowptr = (int*)  alloc((N_NODES + 1) * sizeof(int));
    float* dinv   = (float*)alloc(N_NODES * sizeof(float));
    float* W12    = (float*)alloc(IN_H * OUT_H * sizeof(float));
    float* bb     = (float*)alloc(OUT_H * sizeof(float));
    unsigned int* Pp  = (unsigned int*)alloc((size_t)N_NODES * 32);       // bf16 rows, 3.2 MB
    unsigned int* Z1p = (unsigned int*)alloc((size_t)N_NODES * 32);       // bf16 rows, 3.2 MB

    const int B = 256;
    int gN4 = (N_NODES * 4 + B - 1) / B;        // 4 lanes per node

    k_w12    <<<1, B, 0, stream>>>(W1, b1, W2, W12, bb);
    k_hist   <<<NBLK, B, 0, stream>>>(ei + N_EDGES, bh, N_EDGES);
    k_btot   <<<NB, 256, 0, stream>>>(bh, btot);
    k_boff   <<<NB, 1024, 0, stream>>>(bh, btot, bstart);
    k_bucket <<<NBLK, B, 0, stream>>>(ei, bh, packed, N_EDGES);
    k_sort   <<<NB, 1024, 0, stream>>>(packed, bstart, X, W12, col, rowptr, dinv, Pp);
    k_gather1<<<gN4, B, 0, stream>>>(rowptr, col, dinv, Pp, Z1p, rvec, N_NODES);
    k_g2d    <<<gN4, B, 0, stream>>>(rowptr, col, dinv, Z1p, rvec, bb, b2, emb_a,
                                     Wc, bc, out, N_NODES);
}

// Round 8
// 108.609 us; speedup vs baseline: 1.6516x; 1.0365x over previous
//
#include <hip/hip_runtime.h>

#define N_NODES 100000
#define N_EDGES 1600000
#define IN_H 18
#define OUT_H 11
#define NCLASS 40
#define NHID 256
// P'/Z1' rows: 16 bf16 elems = 32B. elems 0..10 features, 11 = dinv (P'), 12..15 pad.

// ---- bucket-sort geometry ----
#define BBITS 9
#define BINS 512
#define NB 196                              // ceil(100000/512)
#define NBLK 800
#define CHUNK 2000                          // NBLK*CHUNK == N_EDGES; 2000%4==0
#define SRC_MASK 0x1FFFF

// ---- bf16 helpers (storage-only quantization, f32 accumulate) ----
__device__ __forceinline__ float bflo(unsigned u) { return __uint_as_float(u << 16); }
__device__ __forceinline__ float bfhi(unsigned u) { return __uint_as_float(u & 0xFFFF0000u); }
__device__ __forceinline__ unsigned bfr(float x) {             // f32 -> bf16 bits, RNE
    unsigned u = __float_as_uint(x);
    return (u + 0x7FFFu + ((u >> 16) & 1u)) >> 16;
}
__device__ __forceinline__ unsigned bfpack(float a, float b) { return bfr(a) | (bfr(b) << 16); }
__device__ __forceinline__ float4 bfunpack4(uint2 w) {
    return make_float4(bflo(w.x), bfhi(w.x), bflo(w.y), bfhi(w.y));
}

// ---------------- K1a: per-block bucket histogram (LDS atomics only) ----------------
__global__ void k_hist(const int* __restrict__ dst, int* __restrict__ bh, int E) {
    __shared__ int h[NB];
    int t = threadIdx.x;
    if (t < NB) h[t] = 0;
    __syncthreads();
    const int4* d4 = (const int4*)(dst + blockIdx.x * CHUNK);
    for (int i = t; i < CHUNK / 4; i += blockDim.x) {
        int4 w = d4[i];
        atomicAdd(&h[w.x >> BBITS], 1);
        atomicAdd(&h[w.y >> BBITS], 1);
        atomicAdd(&h[w.z >> BBITS], 1);
        atomicAdd(&h[w.w >> BBITS], 1);
    }
    __syncthreads();
    if (t < NB) bh[t * NBLK + blockIdx.x] = h[t];   // [bin][blk]
}

// ---------------- S1: bucket totals ----------------
__global__ void k_btot(const int* __restrict__ bh, int* __restrict__ btot) {
    __shared__ int s[256];
    int b = blockIdx.x, t = threadIdx.x;
    int sum = 0;
    for (int k = t; k < NBLK; k += 256) sum += bh[b * NBLK + k];
    s[t] = sum;
    __syncthreads();
    for (int off = 128; off > 0; off >>= 1) {
        if (t < off) s[t] += s[t + off];
        __syncthreads();
    }
    if (t == 0) btot[b] = s[0];
}

// ---------------- S2+S3 fused: per-(bin,blk) absolute offsets + bstart ----------------
__global__ __launch_bounds__(1024) void k_boff(int* __restrict__ bh,
                                               const int* __restrict__ btot,
                                               int* __restrict__ bstart) {
    __shared__ int s0[1024], s1[1024];
    __shared__ int bt0[256], bt1[256];
    int b = blockIdx.x, t = threadIdx.x;
    if (t < 256) bt0[t] = (t < NB) ? btot[t] : 0;
    __syncthreads();
    int* c0 = bt0; int* c1 = bt1;
    for (int off = 1; off < 256; off <<= 1) {
        if (t < 256) c1[t] = c0[t] + ((t >= off) ? c0[t - off] : 0);
        __syncthreads();
        int* tmp = c0; c0 = c1; c1 = tmp;
    }
    int base = c0[b] - btot[b];              // exclusive prefix = bucket base
    if (t == 0) {
        bstart[b] = base;
        if (b == 0) bstart[NB] = N_EDGES;
    }
    int v = (t < NBLK) ? bh[b * NBLK + t] : 0;
    s0[t] = v;
    __syncthreads();
    int* c = s0; int* n = s1;
    for (int off = 1; off < 1024; off <<= 1) {
        n[t] = c[t] + ((t >= off) ? c[t - off] : 0);
        __syncthreads();
        int* tmp = c; c = n; n = tmp;
    }
    if (t < NBLK) bh[b * NBLK + t] = c[t] - v + base;
}

// ---------------- K1c: scatter edges into buckets (LDS cursors) ----------------
__global__ void k_bucket(const int* __restrict__ ei, const int* __restrict__ bh,
                         unsigned int* __restrict__ packed, int E) {
    __shared__ int cur[NB];
    int t = threadIdx.x;
    if (t < NB) cur[t] = bh[t * NBLK + blockIdx.x];
    __syncthreads();
    int base = blockIdx.x * CHUNK;
    const int4* s4 = (const int4*)(ei + base);
    const int4* d4 = (const int4*)(ei + E + base);
    for (int i = t; i < CHUNK / 4; i += blockDim.x) {
        int4 s = s4[i];
        int4 d = d4[i];
        int sl;
        sl = atomicAdd(&cur[d.x >> BBITS], 1);
        packed[sl] = ((unsigned)(d.x & (BINS - 1)) << 17) | (unsigned)s.x;
        sl = atomicAdd(&cur[d.y >> BBITS], 1);
        packed[sl] = ((unsigned)(d.y & (BINS - 1)) << 17) | (unsigned)s.y;
        sl = atomicAdd(&cur[d.z >> BBITS], 1);
        packed[sl] = ((unsigned)(d.z & (BINS - 1)) << 17) | (unsigned)s.z;
        sl = atomicAdd(&cur[d.w >> BBITS], 1);
        packed[sl] = ((unsigned)(d.w & (BINS - 1)) << 17) | (unsigned)s.w;
    }
}

// ---------------- W12 = W1 @ W2, bb = b1 @ W2 (one block) ----------------
__global__ void k_w12(const float* __restrict__ W1, const float* __restrict__ b1,
                      const float* __restrict__ W2,
                      float* __restrict__ W12, float* __restrict__ bb) {
    int t = threadIdx.x;
    if (t < IN_H * OUT_H) {
        int i = t / OUT_H, j = t % OUT_H;
        float s = 0.f;
        for (int k = 0; k < NHID; ++k) s += W1[i * NHID + k] * W2[k * OUT_H + j];
        W12[t] = s;
    } else if (t < IN_H * OUT_H + OUT_H) {
        int j = t - IN_H * OUT_H;
        float s = 0.f;
        for (int k = 0; k < NHID; ++k) s += b1[k] * W2[k * OUT_H + j];
        bb[j] = s;
    }
}

// ---------------- K2: per-bucket counting sort -> col, rowptr, dinv, P'(bf16) ----------------
__global__ __launch_bounds__(1024)
void k_sort(const unsigned int* __restrict__ packed, const int* __restrict__ bstart,
            const float* __restrict__ X, const float* __restrict__ W12g,
            int* __restrict__ col, int* __restrict__ rowptr,
            float* __restrict__ dinv, unsigned int* __restrict__ Pp) {
    __shared__ int hist[BINS];
    __shared__ int s0[BINS], s1[BINS];
    __shared__ int cur[BINS];
    __shared__ float sW[IN_H * OUT_H];
    int b = blockIdx.x, t = threadIdx.x;
    int beg = bstart[b], end = bstart[b + 1];
    if (t < BINS) hist[t] = 0;
    if (t >= BINS && t < BINS + IN_H * OUT_H) sW[t - BINS] = W12g[t - BINS];
    __syncthreads();
    for (int i = beg + t; i < end; i += blockDim.x)
        atomicAdd(&hist[packed[i] >> 17], 1);
    __syncthreads();
    if (t < BINS) s0[t] = hist[t];
    __syncthreads();
    int* c = s0; int* n = s1;
    for (int off = 1; off < BINS; off <<= 1) {
        if (t < BINS) n[t] = c[t] + ((t >= off) ? c[t - off] : 0);
        __syncthreads();
        int* tmp = c; c = n; n = tmp;
    }
    if (t < BINS) {
        int excl = c[t] - hist[t];
        int gbase = beg + excl;
        cur[t] = gbase;
        int node = (b << BBITS) + t;
        if (node <= N_NODES) rowptr[node] = gbase;
        if (node < N_NODES)  dinv[node] = rsqrtf((float)(hist[t] + 1));
    }
    __syncthreads();
    for (int i = beg + t; i < end; i += blockDim.x) {
        unsigned p = packed[i];
        int slot = atomicAdd(&cur[p >> 17], 1);
        col[slot] = (int)(p & SRC_MASK);
    }
    // ---- fused P' (bf16 rows, 32B) ----
    int node = (b << BBITS) + t;
    if (t < BINS && node < N_NODES) {
        float dv = rsqrtf((float)(hist[t] + 1));
        float x[IN_H];
        const float2* xr = (const float2*)(X + (size_t)node * IN_H);
        #pragma unroll
        for (int k = 0; k < IN_H / 2; ++k) {
            float2 cc = xr[k];
            x[2 * k] = cc.x; x[2 * k + 1] = cc.y;
        }
        float pf[12];
        #pragma unroll
        for (int j = 0; j < OUT_H; ++j) {
            float s = 0.f;
            #pragma unroll
            for (int k = 0; k < IN_H; ++k) s += x[k] * sW[k * OUT_H + j];
            pf[j] = dv * s;
        }
        pf[11] = dv;                          // dinv folded in as "feature 11"
        uint4* pw = (uint4*)(Pp + (size_t)node * 8);
        pw[0] = make_uint4(bfpack(pf[0], pf[1]), bfpack(pf[2], pf[3]),
                           bfpack(pf[4], pf[5]), bfpack(pf[6], pf[7]));
        pw[1] = make_uint4(bfpack(pf[8], pf[9]), bfpack(pf[10], pf[11]), 0u, 0u);
    }
}

// ---------------- gather pass 1: 8 lanes/node (2 edge-quads), bf16 rows ----------------
__global__ void k_gather1(const int* __restrict__ rowptr, const int* __restrict__ col,
                          const float* __restrict__ dinv, const unsigned int* __restrict__ Pp,
                          unsigned int* __restrict__ Z1p, float* __restrict__ r, int n) {
    int g = blockIdx.x * blockDim.x + threadIdx.x;
    int v = g >> 3;
    if (v >= n) return;
    int sub  = (g >> 2) & 1;    // edge-quad id
    int lane = g & 3;           // feature quarter
    int beg = rowptr[v], end = rowptr[v + 1];
    int half = (end - beg) >> 1;
    int qbeg = beg + (sub ? half : 0);
    int qend = sub ? end : beg + half;
    float4 acc = make_float4(0.f, 0.f, 0.f, 0.f);
    const uint2* P2 = (const uint2*)Pp;       // 4 uint2 per 32B row
    int e = qbeg;
    for (; e + 3 < qend; e += 4) {
        int i0 = col[e], i1 = col[e + 1], i2 = col[e + 2], i3 = col[e + 3];
        float4 a0 = bfunpack4(P2[(size_t)i0 * 4 + lane]);
        float4 a1 = bfunpack4(P2[(size_t)i1 * 4 + lane]);
        float4 a2 = bfunpack4(P2[(size_t)i2 * 4 + lane]);
        float4 a3 = bfunpack4(P2[(size_t)i3 * 4 + lane]);
        acc.x += a0.x + a1.x + a2.x + a3.x;
        acc.y += a0.y + a1.y + a2.y + a3.y;
        acc.z += a0.z + a1.z + a2.z + a3.z;
        acc.w += a0.w + a1.w + a2.w + a3.w;
    }
    for (; e < qend; ++e) {
        float4 a = bfunpack4(P2[(size_t)col[e] * 4 + lane]);
        acc.x += a.x; acc.y += a.y; acc.z += a.z; acc.w += a.w;
    }
    if (!sub) {   // self-loop once
        float4 a = bfunpack4(P2[(size_t)v * 4 + lane]);
        acc.x += a.x; acc.y += a.y; acc.z += a.z; acc.w += a.w;
    }
    // combine the two edge-quads
    acc.x += __shfl_xor(acc.x, 4, 8);
    acc.y += __shfl_xor(acc.y, 4, 8);
    acc.z += __shfl_xor(acc.z, 4, 8);
    acc.w += __shfl_xor(acc.w, 4, 8);
    if (!sub) {
        float dd = dinv[v];
        float s2 = dd * dd;
        ((uint2*)Z1p)[(size_t)v * 4 + lane] =
            make_uint2(bfpack(s2 * acc.x, s2 * acc.y), bfpack(s2 * acc.z, s2 * acc.w));
        if (lane == 2) r[v] = dd * acc.w;   // acc.w(lane2) = sum dinv[src] + dinv[v]
    }
}

// ---------------- gather pass 2 FUSED with dense epilogue: 8 lanes/node ----------------
__global__ void k_g2d(const int* __restrict__ rowptr, const int* __restrict__ col,
                      const float* __restrict__ dinv, const unsigned int* __restrict__ Z1p,
                      const float* __restrict__ r, const float* __restrict__ bbg,
                      const float* __restrict__ b2g, const float* __restrict__ emb_a,
                      const float* __restrict__ Wc, const float* __restrict__ bc,
                      float* __restrict__ out, int n) {
    __shared__ float sWc[(NCLASS + OUT_H) * NCLASS];   // 51*40 = 2040
    __shared__ float sbc[NCLASS];
    __shared__ float sbb[16];
    __shared__ float sb2[16];
    for (int t = threadIdx.x; t < (NCLASS + OUT_H) * NCLASS; t += blockDim.x) sWc[t] = Wc[t];
    if (threadIdx.x < NCLASS) sbc[threadIdx.x] = bc[threadIdx.x];
    if (threadIdx.x < 16) {
        sbb[threadIdx.x] = (threadIdx.x < OUT_H) ? bbg[threadIdx.x] : 0.f;
        sb2[threadIdx.x] = (threadIdx.x < OUT_H) ? b2g[threadIdx.x] : 0.f;
    }
    __syncthreads();
    int g = blockIdx.x * blockDim.x + threadIdx.x;
    int v = g >> 3;
    if (v >= n) return;
    int sub   = (g >> 2) & 1;   // edge-quad id
    int lane  = g & 3;          // feature quarter
    int lane8 = g & 7;          // dense j-split id
    int beg = rowptr[v], end = rowptr[v + 1];
    int half = (end - beg) >> 1;
    int qbeg = beg + (sub ? half : 0);
    int qend = sub ? end : beg + half;
    float4 acc = make_float4(0.f, 0.f, 0.f, 0.f);
    const uint2* Z2 = (const uint2*)Z1p;
    int e = qbeg;
    for (; e + 3 < qend; e += 4) {
        int i0 = col[e], i1 = col[e + 1], i2 = col[e + 2], i3 = col[e + 3];
        float4 a0 = bfunpack4(Z2[(size_t)i0 * 4 + lane]);
        float4 a1 = bfunpack4(Z2[(size_t)i1 * 4 + lane]);
        float4 a2 = bfunpack4(Z2[(size_t)i2 * 4 + lane]);
        float4 a3 = bfunpack4(Z2[(size_t)i3 * 4 + lane]);
        acc.x += a0.x + a1.x + a2.x + a3.x;
        acc.y += a0.y + a1.y + a2.y + a3.y;
        acc.z += a0.z + a1.z + a2.z + a3.z;
        acc.w += a0.w + a1.w + a2.w + a3.w;
    }
    for (; e < qend; ++e) {
        float4 a = bfunpack4(Z2[(size_t)col[e] * 4 + lane]);
        acc.x += a.x; acc.y += a.y; acc.z += a.z; acc.w += a.w;
    }
    if (!sub) {
        float4 a = bfunpack4(Z2[(size_t)v * 4 + lane]);
        acc.x += a.x; acc.y += a.y; acc.z += a.z; acc.w += a.w;
    }
    acc.x += __shfl_xor(acc.x, 4, 8);
    acc.y += __shfl_xor(acc.y, 4, 8);
    acc.z += __shfl_xor(acc.z, 4, 8);
    acc.w += __shfl_xor(acc.w, 4, 8);
    float dd = dinv[v];
    float rv = r[v];
    float af[4] = {acc.x, acc.y, acc.z, acc.w};
    float hloc[4];
    #pragma unroll
    for (int c = 0; c < 4; ++c) {
        int f = 4 * lane + c;                 // f in [0,15]; >=11 is pad (zero biases)
        float tv = dd * af[c] + rv * sbb[f] + sb2[f];
        hloc[c] = tv > 0.f ? tv : 0.f;
    }
    // broadcast the 11 h features within each quad (both quads hold identical hloc)
    float hall[OUT_H];
    #pragma unroll
    for (int f = 0; f < OUT_H; ++f)
        hall[f] = __shfl(hloc[f & 3], f >> 2, 4);
    // j-split dense: lane8 owns output columns [5*lane8, 5*lane8+5)
    const int jb = 5 * lane8;
    float o[5];
    #pragma unroll
    for (int j = 0; j < 5; ++j) o[j] = sbc[jb + j];
    const float4* ea4 = (const float4*)(emb_a + (size_t)v * NCLASS);
    #pragma unroll
    for (int k4 = 0; k4 < NCLASS / 4; ++k4) {
        float4 a = ea4[k4];                   // same addr across 8 lanes -> broadcast
        const float* w0 = &sWc[(4 * k4 + 0) * NCLASS + jb];
        const float* w1 = &sWc[(4 * k4 + 1) * NCLASS + jb];
        const float* w2 = &sWc[(4 * k4 + 2) * NCLASS + jb];
        const float* w3 = &sWc[(4 * k4 + 3) * NCLASS + jb];
        #pragma unroll
        for (int j = 0; j < 5; ++j)
            o[j] += a.x * w0[j] + a.y * w1[j] + a.z * w2[j] + a.w * w3[j];
    }
    #pragma unroll
    for (int f = 0; f < OUT_H; ++f) {
        const float* w = &sWc[(NCLASS + f) * NCLASS + jb];
        float hv = hall[f];
        #pragma unroll
        for (int j = 0; j < 5; ++j) o[j] += hv * w[j];
    }
    float* orow = out + (size_t)v * NCLASS + jb;   // 8 lanes write 160B contiguous
    #pragma unroll
    for (int j = 0; j < 5; ++j) orow[j] = o[j];
}

extern "C" void kernel_launch(void* const* d_in, const int* in_sizes, int n_in,
                              void* d_out, int out_size, void* d_ws, size_t ws_size,
                              hipStream_t stream) {
    const float* X     = (const float*)d_in[0];
    const int*   ei    = (const int*)d_in[1];
    const float* emb_a = (const float*)d_in[2];
    const float* W1    = (const float*)d_in[3];
    const float* b1    = (const float*)d_in[4];
    const float* W2    = (const float*)d_in[5];
    const float* b2    = (const float*)d_in[6];
    const float* Wc    = (const float*)d_in[7];
    const float* bc    = (const float*)d_in[8];
    float* out = (float*)d_out;

    char* ws = (char*)d_ws;
    size_t off = 0;
    auto alloc = [&](size_t nbytes) {
        void* p = (void*)(ws + off);
        off += ((nbytes + 255) / 256) * 256;
        return p;
    };
    // bh dead after k_bucket -> rvec aliases it.
    char* bh_base = (char*)alloc((size_t)NB * NBLK * sizeof(int));        // 627 KB
    int*   bh     = (int*)bh_base;
    float* rvec   = (float*)bh_base;
    int*   btot   = (int*)  alloc(NB * sizeof(int));
    int*   bstart = (int*)  alloc((NB + 1) * sizeof(int));
    unsigned int* packed = (unsigned int*)alloc((size_t)N_EDGES * sizeof(unsigned int));
    int*   col    = (int*)  alloc((size_t)N_EDGES * sizeof(int));
    int*   rowptr = (int*)  alloc((N_NODES + 1) * sizeof(int));
    float* dinv   = (float*)alloc(N_NODES * sizeof(float));
    float* W12    = (float*)alloc(IN_H * OUT_H * sizeof(float));
    float* bb     = (float*)alloc(OUT_H * sizeof(float));
    unsigned int* Pp  = (unsigned int*)alloc((size_t)N_NODES * 32);       // bf16 rows, 3.2 MB
    unsigned int* Z1p = (unsigned int*)alloc((size_t)N_NODES * 32);       // bf16 rows, 3.2 MB

    const int B = 256;
    int gN8 = (N_NODES * 8 + B - 1) / B;        // 8 lanes per node

    k_w12    <<<1, B, 0, stream>>>(W1, b1, W2, W12, bb);
    k_hist   <<<NBLK, B, 0, stream>>>(ei + N_EDGES, bh, N_EDGES);
    k_btot   <<<NB, 256, 0, stream>>>(bh, btot);
    k_boff   <<<NB, 1024, 0, stream>>>(bh, btot, bstart);
    k_bucket <<<NBLK, B, 0, stream>>>(ei, bh, packed, N_EDGES);
    k_sort   <<<NB, 1024, 0, stream>>>(packed, bstart, X, W12, col, rowptr, dinv, Pp);
    k_gather1<<<gN8, B, 0, stream>>>(rowptr, col, dinv, Pp, Z1p, rvec, N_NODES);
    k_g2d    <<<gN8, B, 0, stream>>>(rowptr, col, dinv, Z1p, rvec, bb, b2, emb_a,
                                     Wc, bc, out, N_NODES);
}